// Round 10
// baseline (768.531 us; speedup 1.0000x reference)
//
#include <hip/hip_runtime.h>

#define H  64
#define TT 512
#define BB 512

typedef _Float16 half8 __attribute__((ext_vector_type(8)));
typedef float    f32x4 __attribute__((ext_vector_type(4)));

__device__ __forceinline__ float frcp(float x) { return __builtin_amdgcn_rcpf(x); }
__device__ __forceinline__ float sigm(float x) { return frcp(1.f + __expf(-x)); }
__device__ __forceinline__ float tanh_fast(float x) { return 1.f - 2.f * frcp(__expf(2.f * x) + 1.f); }

#define CSTR 80   // hbuf chain stride (halves): 160B = 40 words -> 2-way max aliasing

// ---------------------------------------------------------------------------
// xpad: [B*T][32] fp16, cols 0..3 = x (fp32->fp16), cols 4..31 = 0.
// ---------------------------------------------------------------------------
__global__ __launch_bounds__(256) void xpad_prep(const float* __restrict__ x,
                                                 _Float16* __restrict__ xpad) {
    int gid = blockIdx.x * 256 + threadIdx.x;
    int row = gid >> 2, q = gid & 3;
    half8 v = {0,0,0,0,0,0,0,0};
    if (q == 0) {
        float4 xv = ((const float4*)x)[row];
        v[0] = (_Float16)xv.x; v[1] = (_Float16)xv.y;
        v[2] = (_Float16)xv.z; v[3] = (_Float16)xv.w;
    }
    *(half8*)(xpad + (size_t)row * 32 + q * 8) = v;
}

// ---------------------------------------------------------------------------
// Layer 0: 4 chains/block, 256 blocks. A=weights, B=data (4 chains x 4 repl).
// Lane (m,q): cell (chain m&3, unit w*16+(m>>2)*4+q). Pipelined: xacc for
// step s+1 computed during s; out0 store deferred to top of next step;
// critical path = ds_read -> 2 dependent h-MFMAs -> activations.
// ---------------------------------------------------------------------------
__global__ __launch_bounds__(256, 1) void lstm_l0(
    const _Float16* __restrict__ xpad,
    const float* __restrict__ WihF, const float* __restrict__ WhhF, const float* __restrict__ bF,
    const float* __restrict__ WihB, const float* __restrict__ WhhB, const float* __restrict__ bB,
    _Float16* __restrict__ out0)
{
    const int dir = blockIdx.x & 1;
    const int b0  = (blockIdx.x >> 1) * 4;
    const int tid = threadIdx.x;
    const int w = tid >> 6, l = tid & 63, m = l & 15, q = l >> 4;
    const int ch = m & 3;
    const int ubo = m >> 2;
    const int uo  = w * 16 + ubo * 4 + q;

    const float* Wih = dir ? WihB : WihF;
    const float* Whh = dir ? WhhB : WhhF;
    const float* bia = dir ? bB   : bF;

    half8 Af[4][3];          // [ub][0,1]=Whh k-windows, [2]=Wih (K=32 padded)
    f32x4 bv[4];
#pragma unroll
    for (int ub = 0; ub < 4; ++ub) {
        const int wrow = (m & 3) * 64 + (w * 16 + ub * 4 + (m >> 2));
#pragma unroll
        for (int s = 0; s < 3; ++s) {
            half8 tmp;
            if (s < 2) {
                const float* src = Whh + wrow * 64 + s * 32 + q * 8;
#pragma unroll
                for (int j = 0; j < 8; ++j) tmp[j] = (_Float16)src[j];
            } else {
#pragma unroll
                for (int j = 0; j < 8; ++j) {
                    int k = q * 8 + j;
                    tmp[j] = (k < 4) ? (_Float16)Wih[wrow * 4 + k] : (_Float16)0.f;
                }
            }
            Af[ub][s] = tmp;
        }
        const int u = w * 16 + ub * 4 + q;
        bv[ub] = (f32x4){bia[u], bia[64 + u], bia[128 + u], bia[192 + u]};
    }

    __shared__ _Float16 hbuf[2][4][CSTR];
    for (int i = tid; i < 2 * 4 * CSTR / 2; i += 256) ((unsigned int*)hbuf)[i] = 0u;
    __syncthreads();

    float c = 0.f, hprev = 0.f;
    const int dt = dir ? -1 : 1;
    int t = dir ? TT - 1 : 0;
    int tprev = t;
    const _Float16* xrow = xpad + (size_t)(b0 + ch) * TT * 32 + q * 8;

    // prologue: xacc for step 0; ax = x for step 1
    half8 ax0 = *(const half8*)(xrow + t * 32);
    f32x4 xacc[4], xaccn[4];
#pragma unroll
    for (int ub = 0; ub < 4; ++ub)
        xacc[ub] = __builtin_amdgcn_mfma_f32_16x16x32_f16(Af[ub][2], ax0, bv[ub], 0, 0, 0);
    int t1 = t + dt; if (t1 < 0 || t1 >= TT) t1 = t;
    half8 ax = *(const half8*)(xrow + t1 * 32);
    int p = 0;

    for (int s = 0; s < TT; ++s) {
        int t2 = t + 2 * dt; if (t2 < 0 || t2 >= TT) t2 = t;
        half8 xl = *(const half8*)(xrow + t2 * 32);
        if (s)
            out0[((size_t)(b0 + ch) * TT + tprev) * 128 + dir * 64 + uo] = (_Float16)hprev;

        half8 ah0 = *(const half8*)&hbuf[p][ch][q * 8];
        half8 ah1 = *(const half8*)&hbuf[p][ch][32 + q * 8];

        f32x4 g_own;
#pragma unroll
        for (int ub = 0; ub < 4; ++ub) {
            f32x4 a = __builtin_amdgcn_mfma_f32_16x16x32_f16(Af[ub][0], ah0, xacc[ub], 0, 0, 0);
            a       = __builtin_amdgcn_mfma_f32_16x16x32_f16(Af[ub][1], ah1, a, 0, 0, 0);
            if (ub == ubo) g_own = a;
        }
        // independent: x-part for step s+1
#pragma unroll
        for (int ub = 0; ub < 4; ++ub)
            xaccn[ub] = __builtin_amdgcn_mfma_f32_16x16x32_f16(Af[ub][2], ax, bv[ub], 0, 0, 0);

        float e_i = sigm(g_own[0]), e_f = sigm(g_own[1]);
        float e_g = tanh_fast(g_own[2]), e_o = sigm(g_own[3]);
        c = e_f * c + e_i * e_g;
        float hh = e_o * tanh_fast(c);
        hprev = hh;

        hbuf[p ^ 1][ch][uo] = (_Float16)hh;
        __syncthreads();
#pragma unroll
        for (int ub = 0; ub < 4; ++ub) xacc[ub] = xaccn[ub];
        ax = xl;
        p ^= 1; tprev = t; t += dt;
    }
    out0[((size_t)(b0 + ch) * TT + tprev) * 128 + dir * 64 + uo] = (_Float16)hprev;
}

// ---------------------------------------------------------------------------
// Layer 1: same scheme; x-part = 4 k-slices from out0, pipelined one step
// ahead; critical path = 2 dependent h-MFMAs. Accumulates hsum.
// ---------------------------------------------------------------------------
__global__ __launch_bounds__(256, 1) void lstm_l1(
    const _Float16* __restrict__ out0,
    const float* __restrict__ WihF, const float* __restrict__ WhhF, const float* __restrict__ bF,
    const float* __restrict__ WihB, const float* __restrict__ WhhB, const float* __restrict__ bB,
    float* __restrict__ pooled)
{
    const int dir = blockIdx.x & 1;
    const int b0  = (blockIdx.x >> 1) * 4;
    const int tid = threadIdx.x;
    const int w = tid >> 6, l = tid & 63, m = l & 15, q = l >> 4;
    const int ch = m & 3;
    const int ubo = m >> 2;
    const int uo  = w * 16 + ubo * 4 + q;

    const float* Wih = dir ? WihB : WihF;
    const float* Whh = dir ? WhhB : WhhF;
    const float* bia = dir ? bB   : bF;

    half8 Af[4][6];          // [ub][0,1]=Whh, [2..5]=Wih
    f32x4 bv[4];
#pragma unroll
    for (int ub = 0; ub < 4; ++ub) {
        const int wrow = (m & 3) * 64 + (w * 16 + ub * 4 + (m >> 2));
#pragma unroll
        for (int s = 0; s < 6; ++s) {
            const float* src = (s < 2) ? (Whh + wrow * 64 + s * 32 + q * 8)
                                       : (Wih + wrow * 128 + (s - 2) * 32 + q * 8);
            half8 tmp;
#pragma unroll
            for (int j = 0; j < 8; ++j) tmp[j] = (_Float16)src[j];
            Af[ub][s] = tmp;
        }
        const int u = w * 16 + ub * 4 + q;
        bv[ub] = (f32x4){bia[u], bia[64 + u], bia[128 + u], bia[192 + u]};
    }

    __shared__ _Float16 hbuf[2][4][CSTR];
    for (int i = tid; i < 2 * 4 * CSTR / 2; i += 256) ((unsigned int*)hbuf)[i] = 0u;
    __syncthreads();

    float c = 0.f, hs = 0.f;
    const int dt = dir ? -1 : 1;
    int t = dir ? TT - 1 : 0;
    const _Float16* xrow = out0 + (size_t)(b0 + ch) * TT * 128 + q * 8;

    // prologue: xacc for step 0; ax = x for step 1
    half8 ax[4], xl[4];
#pragma unroll
    for (int s4 = 0; s4 < 4; ++s4) ax[s4] = *(const half8*)(xrow + t * 128 + s4 * 32);
    f32x4 xacc[4], xaccn[4];
#pragma unroll
    for (int ub = 0; ub < 4; ++ub) {
        f32x4 a = bv[ub];
        a = __builtin_amdgcn_mfma_f32_16x16x32_f16(Af[ub][2], ax[0], a, 0, 0, 0);
        a = __builtin_amdgcn_mfma_f32_16x16x32_f16(Af[ub][3], ax[1], a, 0, 0, 0);
        a = __builtin_amdgcn_mfma_f32_16x16x32_f16(Af[ub][4], ax[2], a, 0, 0, 0);
        xacc[ub] = __builtin_amdgcn_mfma_f32_16x16x32_f16(Af[ub][5], ax[3], a, 0, 0, 0);
    }
    int t1 = t + dt; if (t1 < 0 || t1 >= TT) t1 = t;
#pragma unroll
    for (int s4 = 0; s4 < 4; ++s4) ax[s4] = *(const half8*)(xrow + t1 * 128 + s4 * 32);
    int p = 0;

    for (int s = 0; s < TT; ++s) {
        int t2 = t + 2 * dt; if (t2 < 0 || t2 >= TT) t2 = t;
#pragma unroll
        for (int s4 = 0; s4 < 4; ++s4) xl[s4] = *(const half8*)(xrow + t2 * 128 + s4 * 32);

        half8 ah0 = *(const half8*)&hbuf[p][ch][q * 8];
        half8 ah1 = *(const half8*)&hbuf[p][ch][32 + q * 8];

        f32x4 g_own;
#pragma unroll
        for (int ub = 0; ub < 4; ++ub) {
            f32x4 a = __builtin_amdgcn_mfma_f32_16x16x32_f16(Af[ub][0], ah0, xacc[ub], 0, 0, 0);
            a       = __builtin_amdgcn_mfma_f32_16x16x32_f16(Af[ub][1], ah1, a, 0, 0, 0);
            if (ub == ubo) g_own = a;
        }
        // independent: x-part for step s+1
#pragma unroll
        for (int ub = 0; ub < 4; ++ub) {
            f32x4 a = bv[ub];
            a = __builtin_amdgcn_mfma_f32_16x16x32_f16(Af[ub][2], ax[0], a, 0, 0, 0);
            a = __builtin_amdgcn_mfma_f32_16x16x32_f16(Af[ub][3], ax[1], a, 0, 0, 0);
            a = __builtin_amdgcn_mfma_f32_16x16x32_f16(Af[ub][4], ax[2], a, 0, 0, 0);
            xaccn[ub] = __builtin_amdgcn_mfma_f32_16x16x32_f16(Af[ub][5], ax[3], a, 0, 0, 0);
        }

        float e_i = sigm(g_own[0]), e_f = sigm(g_own[1]);
        float e_g = tanh_fast(g_own[2]), e_o = sigm(g_own[3]);
        c = e_f * c + e_i * e_g;
        float hh = e_o * tanh_fast(c);
        hs += hh;

        hbuf[p ^ 1][ch][uo] = (_Float16)hh;
        __syncthreads();
#pragma unroll
        for (int ub = 0; ub < 4; ++ub) xacc[ub] = xaccn[ub];
#pragma unroll
        for (int s4 = 0; s4 < 4; ++s4) ax[s4] = xl[s4];
        p ^= 1; t += dt;
    }

    pooled[(size_t)(b0 + ch) * 128 + dir * 64 + uo] = hs;
}

// ---------------------------------------------------------------------------
// Head: out[b] = dot(pooled[b], fcw) / T + fcb
// ---------------------------------------------------------------------------
__global__ __launch_bounds__(64) void fc_head(
    const float* __restrict__ pooled,
    const float* __restrict__ fcw, const float* __restrict__ fcb,
    float* __restrict__ out)
{
    const int b = blockIdx.x;
    const int l = threadIdx.x;
    float v = pooled[b * 128 + l] * fcw[l] + pooled[b * 128 + 64 + l] * fcw[64 + l];
#pragma unroll
    for (int o = 32; o > 0; o >>= 1) v += __shfl_down(v, o);
    if (l == 0) out[b] = v * (1.f / (float)TT) + fcb[0];
}

extern "C" void kernel_launch(void* const* d_in, const int* in_sizes, int n_in,
                              void* d_out, int out_size, void* d_ws, size_t ws_size,
                              hipStream_t stream) {
    const float* x       = (const float*)d_in[0];
    const float* Wih_l0f = (const float*)d_in[1];
    const float* Whh_l0f = (const float*)d_in[2];
    const float* b_l0f   = (const float*)d_in[3];
    const float* Wih_l0b = (const float*)d_in[4];
    const float* Whh_l0b = (const float*)d_in[5];
    const float* b_l0b   = (const float*)d_in[6];
    const float* Wih_l1f = (const float*)d_in[7];
    const float* Whh_l1f = (const float*)d_in[8];
    const float* b_l1f   = (const float*)d_in[9];
    const float* Wih_l1b = (const float*)d_in[10];
    const float* Whh_l1b = (const float*)d_in[11];
    const float* b_l1b   = (const float*)d_in[12];
    const float* fcw     = (const float*)d_in[13];
    const float* fcb     = (const float*)d_in[14];

    const size_t o_xpad   = 0;
    const size_t o_out0   = o_xpad + (size_t)BB * TT * 32 * 2;
    const size_t o_pooled = o_out0 + (size_t)BB * TT * 128 * 2;

    _Float16* xpad   = (_Float16*)((char*)d_ws + o_xpad);
    _Float16* out0   = (_Float16*)((char*)d_ws + o_out0);
    float*    pooled = (float*)((char*)d_ws + o_pooled);

    xpad_prep<<<(BB * TT * 4) / 256, 256, 0, stream>>>(x, xpad);
    lstm_l0<<<(BB / 4) * 2, 256, 0, stream>>>(xpad, Wih_l0f, Whh_l0f, b_l0f,
                                              Wih_l0b, Whh_l0b, b_l0b, out0);
    lstm_l1<<<(BB / 4) * 2, 256, 0, stream>>>(out0, Wih_l1f, Whh_l1f, b_l1f,
                                              Wih_l1b, Whh_l1b, b_l1b, pooled);
    fc_head<<<BB, 64, 0, stream>>>(pooled, fcw, fcb, (float*)d_out);
}

// Round 11
// 660.770 us; speedup vs baseline: 1.1631x; 1.1631x over previous
//
#include <hip/hip_runtime.h>

#define H  64
#define TT 512
#define BB 512
#define CSTR 80   // hbuf chain stride in halves: 160B -> max 2-way bank aliasing

typedef _Float16 half8 __attribute__((ext_vector_type(8)));
typedef float    f32x4 __attribute__((ext_vector_type(4)));

__device__ __forceinline__ float frcp(float x) { return __builtin_amdgcn_rcpf(x); }
__device__ __forceinline__ float sigm(float x) { return frcp(1.f + __expf(-x)); }
__device__ __forceinline__ float tanh_fast(float x) { return 1.f - 2.f * frcp(__expf(2.f * x) + 1.f); }

// ---------------------------------------------------------------------------
// xpad: [B*T][32] fp16, cols 0..3 = x (fp32->fp16), cols 4..31 = 0.
// ---------------------------------------------------------------------------
__global__ __launch_bounds__(256) void xpad_prep(const float* __restrict__ x,
                                                 _Float16* __restrict__ xpad) {
    int gid = blockIdx.x * 256 + threadIdx.x;
    int row = gid >> 2, q = gid & 3;
    half8 v = {0,0,0,0,0,0,0,0};
    if (q == 0) {
        float4 xv = ((const float4*)x)[row];
        v[0] = (_Float16)xv.x; v[1] = (_Float16)xv.y;
        v[2] = (_Float16)xv.z; v[3] = (_Float16)xv.w;
    }
    *(half8*)(xpad + (size_t)row * 32 + q * 8) = v;
}

// ---------------------------------------------------------------------------
// Layer 0: C=2 chains/block, 512 blocks -> 2 independent blocks per CU with
// their own barriers; the CU interleaves them to hide the per-step serial
// recurrence latency (the measured ~1900-cyc wall at 1 block/CU).
// A=weights (16 rows = 4 units x 4 gates per ub), B=data (cols: chain=n&1,
// replica=n>>1). Lane (m,q) owns cell (chain m&1, unit w*16+((m>>1)&3)*4+q);
// lanes m>=8 are redundant replicas (stores predicated m<8).
// ---------------------------------------------------------------------------
__global__ __launch_bounds__(256, 2) void lstm_l0(
    const _Float16* __restrict__ xpad,
    const float* __restrict__ WihF, const float* __restrict__ WhhF, const float* __restrict__ bF,
    const float* __restrict__ WihB, const float* __restrict__ WhhB, const float* __restrict__ bB,
    _Float16* __restrict__ out0)
{
    const int dir = blockIdx.x & 1;
    const int b0  = (blockIdx.x >> 1) * 2;           // 2 chains per block
    const int tid = threadIdx.x;
    const int w = tid >> 6, l = tid & 63, m = l & 15, q = l >> 4;
    const int ch  = m & 1;
    const int ubo = (m >> 1) & 3;
    const int uo  = w * 16 + ubo * 4 + q;
    const bool act = (m < 8);

    const float* Wih = dir ? WihB : WihF;
    const float* Whh = dir ? WhhB : WhhF;
    const float* bia = dir ? bB   : bF;

    half8 Af[4][3];          // [ub][0,1]=Whh k-windows, [2]=Wih (K=32 padded)
    f32x4 bv[4];
#pragma unroll
    for (int ub = 0; ub < 4; ++ub) {
        const int wrow = (m & 3) * 64 + (w * 16 + ub * 4 + (m >> 2));  // A row m -> gate m&3
#pragma unroll
        for (int s = 0; s < 3; ++s) {
            half8 tmp;
            if (s < 2) {
                const float* src = Whh + wrow * 64 + s * 32 + q * 8;
#pragma unroll
                for (int j = 0; j < 8; ++j) tmp[j] = (_Float16)src[j];
            } else {
#pragma unroll
                for (int j = 0; j < 8; ++j) {
                    int k = q * 8 + j;
                    tmp[j] = (k < 4) ? (_Float16)Wih[wrow * 4 + k] : (_Float16)0.f;
                }
            }
            Af[ub][s] = tmp;
        }
        const int u = w * 16 + ub * 4 + q;
        bv[ub] = (f32x4){bia[u], bia[64 + u], bia[128 + u], bia[192 + u]};
    }

    __shared__ _Float16 hbuf[2][2][CSTR];            // [pingpong][chain][unit(+pad)]
    for (int i = tid; i < 2 * 2 * CSTR / 2; i += 256) ((unsigned int*)hbuf)[i] = 0u;
    __syncthreads();

    float c = 0.f;
    const int dt = dir ? -1 : 1;
    int t = dir ? TT - 1 : 0;
    const _Float16* xrow = xpad + (size_t)(b0 + ch) * TT * 32 + q * 8;
    half8 ax = *(const half8*)(xrow + t * 32);
    int p = 0;

    for (int s = 0; s < TT; ++s) {
        int tn = t + ((s + 1 < TT) ? dt : 0);
        half8 axn = *(const half8*)(xrow + tn * 32);

        half8 ah0 = *(const half8*)&hbuf[p][ch][q * 8];
        half8 ah1 = *(const half8*)&hbuf[p][ch][32 + q * 8];

        f32x4 g_own;
#pragma unroll
        for (int ub = 0; ub < 4; ++ub) {
            f32x4 a = __builtin_amdgcn_mfma_f32_16x16x32_f16(Af[ub][2], ax,  bv[ub], 0, 0, 0);
            a       = __builtin_amdgcn_mfma_f32_16x16x32_f16(Af[ub][0], ah0, a, 0, 0, 0);
            a       = __builtin_amdgcn_mfma_f32_16x16x32_f16(Af[ub][1], ah1, a, 0, 0, 0);
            if (ub == ubo) g_own = a;
        }

        float e_i = sigm(g_own[0]), e_f = sigm(g_own[1]);
        float e_g = tanh_fast(g_own[2]), e_o = sigm(g_own[3]);
        c = e_f * c + e_i * e_g;
        float hh = e_o * tanh_fast(c);

        if (act) {
            out0[((size_t)(b0 + ch) * TT + t) * 128 + dir * 64 + uo] = (_Float16)hh;
            hbuf[p ^ 1][ch][uo] = (_Float16)hh;
        }
        __syncthreads();
        p ^= 1; t += dt; ax = axn;
    }
}

// ---------------------------------------------------------------------------
// Layer 1: same scheme; K = 128 (x from out0) + 64 (h) = 6 slices, 24 MFMA.
// ---------------------------------------------------------------------------
__global__ __launch_bounds__(256, 2) void lstm_l1(
    const _Float16* __restrict__ out0,
    const float* __restrict__ WihF, const float* __restrict__ WhhF, const float* __restrict__ bF,
    const float* __restrict__ WihB, const float* __restrict__ WhhB, const float* __restrict__ bB,
    float* __restrict__ pooled)
{
    const int dir = blockIdx.x & 1;
    const int b0  = (blockIdx.x >> 1) * 2;
    const int tid = threadIdx.x;
    const int w = tid >> 6, l = tid & 63, m = l & 15, q = l >> 4;
    const int ch  = m & 1;
    const int ubo = (m >> 1) & 3;
    const int uo  = w * 16 + ubo * 4 + q;
    const bool act = (m < 8);

    const float* Wih = dir ? WihB : WihF;
    const float* Whh = dir ? WhhB : WhhF;
    const float* bia = dir ? bB   : bF;

    half8 Af[4][6];          // [ub][0,1]=Whh, [2..5]=Wih
    f32x4 bv[4];
#pragma unroll
    for (int ub = 0; ub < 4; ++ub) {
        const int wrow = (m & 3) * 64 + (w * 16 + ub * 4 + (m >> 2));
#pragma unroll
        for (int s = 0; s < 6; ++s) {
            const float* src = (s < 2) ? (Whh + wrow * 64 + s * 32 + q * 8)
                                       : (Wih + wrow * 128 + (s - 2) * 32 + q * 8);
            half8 tmp;
#pragma unroll
            for (int j = 0; j < 8; ++j) tmp[j] = (_Float16)src[j];
            Af[ub][s] = tmp;
        }
        const int u = w * 16 + ub * 4 + q;
        bv[ub] = (f32x4){bia[u], bia[64 + u], bia[128 + u], bia[192 + u]};
    }

    __shared__ _Float16 hbuf[2][2][CSTR];
    for (int i = tid; i < 2 * 2 * CSTR / 2; i += 256) ((unsigned int*)hbuf)[i] = 0u;
    __syncthreads();

    float c = 0.f, hs = 0.f;
    const int dt = dir ? -1 : 1;
    int t = dir ? TT - 1 : 0;
    const _Float16* xrow = out0 + (size_t)(b0 + ch) * TT * 128 + q * 8;

    half8 ax[4];
#pragma unroll
    for (int s4 = 0; s4 < 4; ++s4) ax[s4] = *(const half8*)(xrow + t * 128 + s4 * 32);
    int p = 0;

    for (int s = 0; s < TT; ++s) {
        int tn = t + ((s + 1 < TT) ? dt : 0);
        half8 axn[4];
#pragma unroll
        for (int s4 = 0; s4 < 4; ++s4) axn[s4] = *(const half8*)(xrow + tn * 128 + s4 * 32);

        half8 ah0 = *(const half8*)&hbuf[p][ch][q * 8];
        half8 ah1 = *(const half8*)&hbuf[p][ch][32 + q * 8];

        f32x4 g_own;
#pragma unroll
        for (int ub = 0; ub < 4; ++ub) {
            f32x4 a = bv[ub];
            a = __builtin_amdgcn_mfma_f32_16x16x32_f16(Af[ub][2], ax[0], a, 0, 0, 0);
            a = __builtin_amdgcn_mfma_f32_16x16x32_f16(Af[ub][3], ax[1], a, 0, 0, 0);
            a = __builtin_amdgcn_mfma_f32_16x16x32_f16(Af[ub][4], ax[2], a, 0, 0, 0);
            a = __builtin_amdgcn_mfma_f32_16x16x32_f16(Af[ub][5], ax[3], a, 0, 0, 0);
            a = __builtin_amdgcn_mfma_f32_16x16x32_f16(Af[ub][0], ah0,   a, 0, 0, 0);
            a = __builtin_amdgcn_mfma_f32_16x16x32_f16(Af[ub][1], ah1,   a, 0, 0, 0);
            if (ub == ubo) g_own = a;
        }

        float e_i = sigm(g_own[0]), e_f = sigm(g_own[1]);
        float e_g = tanh_fast(g_own[2]), e_o = sigm(g_own[3]);
        c = e_f * c + e_i * e_g;
        float hh = e_o * tanh_fast(c);
        hs += hh;

        if (act) hbuf[p ^ 1][ch][uo] = (_Float16)hh;
        __syncthreads();
        p ^= 1; t += dt;
#pragma unroll
        for (int s4 = 0; s4 < 4; ++s4) ax[s4] = axn[s4];
    }

    if (act) pooled[(size_t)(b0 + ch) * 128 + dir * 64 + uo] = hs;
}

// ---------------------------------------------------------------------------
// Head: out[b] = dot(pooled[b], fcw) / T + fcb
// ---------------------------------------------------------------------------
__global__ __launch_bounds__(64) void fc_head(
    const float* __restrict__ pooled,
    const float* __restrict__ fcw, const float* __restrict__ fcb,
    float* __restrict__ out)
{
    const int b = blockIdx.x;
    const int l = threadIdx.x;
    float v = pooled[b * 128 + l] * fcw[l] + pooled[b * 128 + 64 + l] * fcw[64 + l];
#pragma unroll
    for (int o = 32; o > 0; o >>= 1) v += __shfl_down(v, o);
    if (l == 0) out[b] = v * (1.f / (float)TT) + fcb[0];
}

extern "C" void kernel_launch(void* const* d_in, const int* in_sizes, int n_in,
                              void* d_out, int out_size, void* d_ws, size_t ws_size,
                              hipStream_t stream) {
    const float* x       = (const float*)d_in[0];
    const float* Wih_l0f = (const float*)d_in[1];
    const float* Whh_l0f = (const float*)d_in[2];
    const float* b_l0f   = (const float*)d_in[3];
    const float* Wih_l0b = (const float*)d_in[4];
    const float* Whh_l0b = (const float*)d_in[5];
    const float* b_l0b   = (const float*)d_in[6];
    const float* Wih_l1f = (const float*)d_in[7];
    const float* Whh_l1f = (const float*)d_in[8];
    const float* b_l1f   = (const float*)d_in[9];
    const float* Wih_l1b = (const float*)d_in[10];
    const float* Whh_l1b = (const float*)d_in[11];
    const float* b_l1b   = (const float*)d_in[12];
    const float* fcw     = (const float*)d_in[13];
    const float* fcb     = (const float*)d_in[14];

    const size_t o_xpad   = 0;
    const size_t o_out0   = o_xpad + (size_t)BB * TT * 32 * 2;
    const size_t o_pooled = o_out0 + (size_t)BB * TT * 128 * 2;

    _Float16* xpad   = (_Float16*)((char*)d_ws + o_xpad);
    _Float16* out0   = (_Float16*)((char*)d_ws + o_out0);
    float*    pooled = (float*)((char*)d_ws + o_pooled);

    xpad_prep<<<(BB * TT * 4) / 256, 256, 0, stream>>>(x, xpad);
    lstm_l0<<<(BB / 2) * 2, 256, 0, stream>>>(xpad, Wih_l0f, Whh_l0f, b_l0f,
                                              Wih_l0b, Whh_l0b, b_l0b, out0);
    lstm_l1<<<(BB / 2) * 2, 256, 0, stream>>>(out0, Wih_l1f, Whh_l1f, b_l1f,
                                              Wih_l1b, Whh_l1b, b_l1b, pooled);
    fc_head<<<BB, 64, 0, stream>>>(pooled, fcw, fcb, (float*)d_out);
}